// Round 2
// baseline (562.936 us; speedup 1.0000x reference)
//
#include <hip/hip_runtime.h>
#include <stdint.h>

#define N_COLS  32768
#define N_ROWS  256
#define N_TASKS 512          // 256 rows x {predictions, targets}
#define B1      2048         // level-1 bins (top 11 bits of key)
#define SHIFT1  21
#define SHIFT2  13           // level-2 bins: bits [20:13]
#define MASK2   255u
#define B2      256
#define SMALL_THR 64u
#define CAP     4096         // max LDS-stageable bucket (expected max ~1900)
#define HREP    4            // per-wave histogram/cursor replicas (contention split)
#define HTOT    (B1 * HREP)  // 8192 u32 per task

// order-preserving float->uint32 key
__device__ __forceinline__ uint32_t fkey(float x) {
    uint32_t u = __float_as_uint(x);
    return u ^ ((uint32_t)((int32_t)u >> 31) | 0x80000000u);
}

__device__ __forceinline__ const float* task_src(int t, const float* P, const float* Tg) {
    return (t < N_ROWS ? P : Tg) + (size_t)(t & (N_ROWS - 1)) * N_COLS;
}

// ---------------- K1: per-task histogram, 4 replicas per bin ----------------
// NOTE: element->replica mapping (512 threads, j4 stride 512, rep=(tid>>6)&3)
// MUST match k_scatter exactly — per-replica cursor ranges depend on it.
__global__ void __launch_bounds__(512) k_hist(const float* P, const float* Tg, uint32_t* hist) {
    int t = blockIdx.x;
    const float* src = task_src(t, P, Tg);
    __shared__ uint32_t h[HTOT];
    for (int i = threadIdx.x; i < HTOT; i += 512) h[i] = 0;
    __syncthreads();
    int rep = (threadIdx.x >> 6) & 3;
    for (int j4 = threadIdx.x; j4 < N_COLS / 4; j4 += 512) {
        float4 v = ((const float4*)src)[j4];
        atomicAdd(&h[((fkey(v.x) >> SHIFT1) << 2) + rep], 1u);
        atomicAdd(&h[((fkey(v.y) >> SHIFT1) << 2) + rep], 1u);
        atomicAdd(&h[((fkey(v.z) >> SHIFT1) << 2) + rep], 1u);
        atomicAdd(&h[((fkey(v.w) >> SHIFT1) << 2) + rep], 1u);
    }
    __syncthreads();
    uint32_t* o = hist + (size_t)t * HTOT;
    for (int i = threadIdx.x; i < HTOT; i += 512) o[i] = h[i];
}

// ---------------- K2: per-task exclusive prefix -> per-replica cursors + work lists ----------------
__global__ void __launch_bounds__(256) k_scan(uint32_t* hist, uint32_t* cnts,
                                              unsigned long long* list, unsigned long long* slist) {
    int t = blockIdx.x;
    uint4* h4 = (uint4*)(hist + (size_t)t * HTOT);
    __shared__ uint32_t stmp[256];
    uint32_t run = 0;
    for (int c = 0; c < B1 / 256; ++c) {
        int bin = c * 256 + threadIdx.x;
        uint4 hv = h4[bin];
        uint32_t v = hv.x + hv.y + hv.z + hv.w;
        stmp[threadIdx.x] = v;
        __syncthreads();
        for (int off = 1; off < 256; off <<= 1) {
            uint32_t x = (threadIdx.x >= (unsigned)off) ? stmp[threadIdx.x - off] : 0u;
            __syncthreads();
            stmp[threadIdx.x] += x;
            __syncthreads();
        }
        uint32_t incl = stmp[threadIdx.x];
        uint32_t tot  = stmp[255];
        uint32_t start = run + incl - v;     // task-local exclusive prefix (bucket start)
        if (v > SMALL_THR) {
            uint32_t p = atomicAdd(&cnts[0], 1u);
            list[p] = ((unsigned long long)t << 32) | ((unsigned long long)start << 16) | v;
        } else if (v > 0u) {
            uint32_t p = atomicAdd(&cnts[1], 1u);
            slist[p] = ((unsigned long long)t << 32) | ((unsigned long long)start << 16) | v;
        }
        uint4 w;                              // per-replica cursor starts
        w.x = start;
        w.y = w.x + hv.x;
        w.z = w.y + hv.y;
        w.w = w.z + hv.z;
        h4[bin] = w;
        run += tot;
        __syncthreads();
    }
}

// ---------------- K3: counting-sort scatter, LDS cursors ----------------
__global__ void __launch_bounds__(512) k_scatter(const float* P, const float* Tg, const uint32_t* hist,
                                                 uint32_t* bkey, uint16_t* bidx) {
    int t = blockIdx.x;
    const float* src = task_src(t, P, Tg);
    const uint32_t* h = hist + (size_t)t * HTOT;
    __shared__ uint32_t sc[HTOT];
    for (int i = threadIdx.x; i < HTOT; i += 512) sc[i] = h[i];
    __syncthreads();
    int rep = (threadIdx.x >> 6) & 3;         // must match k_hist
    size_t base = (size_t)t << 15;
    for (int j4 = threadIdx.x; j4 < N_COLS / 4; j4 += 512) {
        float4 v = ((const float4*)src)[j4];
        float xs[4] = {v.x, v.y, v.z, v.w};
#pragma unroll
        for (int c = 0; c < 4; ++c) {
            uint32_t k = fkey(xs[c]);
            uint32_t pos = atomicAdd(&sc[((k >> SHIFT1) << 2) + rep], 1u);
            if (bkey) bkey[base + pos] = k;
            bidx[base + pos] = (uint16_t)(j4 * 4 + c);
        }
    }
}

// ---------------- K4: rank elements of large buckets (m > 64) ----------------
__global__ void __launch_bounds__(256) k_large(const float* P, const float* Tg,
                                               const uint32_t* bkey, const uint16_t* bidx,
                                               uint16_t* ranks,
                                               const uint32_t* cnts, const unsigned long long* list) {
    __shared__ uint32_t sk[CAP];
    __shared__ uint16_t si[CAP];
    __shared__ uint32_t sk2[CAP];
    __shared__ uint16_t si2[CAP];
    __shared__ uint32_t sh[B2];
    __shared__ uint32_t stmp[256];
    uint32_t nlist = cnts[0];
    for (uint32_t e = blockIdx.x; e < nlist; e += gridDim.x) {
        unsigned long long ent = list[e];
        uint32_t t     = (uint32_t)(ent >> 32);
        uint32_t start = (uint32_t)(ent >> 16) & 0xFFFFu;
        uint32_t m     = (uint32_t)ent & 0xFFFFu;
        size_t base = (size_t)t << 15;
        const float* src = task_src((int)t, P, Tg);
        if (m <= CAP) {
            if (threadIdx.x < B2) sh[threadIdx.x] = 0;
            for (uint32_t i = threadIdx.x; i < m; i += 256) {
                uint16_t id = bidx[base + start + i];
                uint32_t k  = bkey ? bkey[base + start + i] : fkey(src[id]);
                si[i] = id; sk[i] = k;
            }
            __syncthreads();
            for (uint32_t i = threadIdx.x; i < m; i += 256)
                atomicAdd(&sh[(sk[i] >> SHIFT2) & MASK2], 1u);
            __syncthreads();
            { // exclusive scan of sh[0..255] (one bin per thread)
                uint32_t v = sh[threadIdx.x];
                stmp[threadIdx.x] = v;
                __syncthreads();
                for (int off = 1; off < 256; off <<= 1) {
                    uint32_t x = (threadIdx.x >= (unsigned)off) ? stmp[threadIdx.x - off] : 0u;
                    __syncthreads();
                    stmp[threadIdx.x] += x;
                    __syncthreads();
                }
                sh[threadIdx.x] = stmp[threadIdx.x] - v;
            }
            __syncthreads();
            for (uint32_t i = threadIdx.x; i < m; i += 256) { // LDS sub-scatter by bits[20:13]
                uint32_t k = sk[i]; uint16_t id = si[i];
                uint32_t pos = atomicAdd(&sh[(k >> SHIFT2) & MASK2], 1u);
                sk2[pos] = k; si2[pos] = id;
            }
            __syncthreads();
            for (uint32_t p2 = threadIdx.x; p2 < m; p2 += 256) {
                uint32_t k = sk2[p2]; uint32_t id = si2[p2];
                uint32_t d2 = (k >> SHIFT2) & MASK2;
                uint32_t gs = d2 ? sh[d2 - 1] : 0u;  // sh now holds inclusive ends
                uint32_t ge = sh[d2];
                uint32_t cnt = 0;
                for (uint32_t q = gs; q < ge; ++q) {   // broadcast reads (same range across lanes)
                    uint32_t kq = sk2[q];
                    cnt += (kq < k || (kq == k && (uint32_t)si2[q] < id)) ? 1u : 0u;
                }
                ranks[base + id] = (uint16_t)(start + gs + cnt);
            }
            __syncthreads();
        } else { // safety fallback; statistically unreachable for these inputs
            for (uint32_t i = threadIdx.x; i < m; i += 256) {
                uint16_t id = bidx[base + start + i];
                uint32_t k  = bkey ? bkey[base + start + i] : fkey(src[id]);
                uint32_t cnt = 0;
                for (uint32_t q = 0; q < m; ++q) {
                    uint16_t iq = bidx[base + start + q];
                    uint32_t kq = bkey ? bkey[base + start + q] : fkey(src[iq]);
                    cnt += (kq < k || (kq == k && iq < id)) ? 1u : 0u;
                }
                ranks[base + id] = (uint16_t)(start + cnt);
            }
            __syncthreads();
        }
    }
}

// ---------------- K5: rank elements of small buckets (1..64) — one wave per list entry ----------------
__global__ void __launch_bounds__(256) k_small(const float* P, const float* Tg,
                                               const uint32_t* bkey, const uint16_t* bidx,
                                               uint16_t* ranks,
                                               const uint32_t* cnts, const unsigned long long* slist) {
    uint32_t gw   = (blockIdx.x * 256u + threadIdx.x) >> 6;
    uint32_t lane = threadIdx.x & 63u;
    uint32_t nw   = (gridDim.x * 256u) >> 6;
    uint32_t nsl  = cnts[1];
    for (uint32_t e = gw; e < nsl; e += nw) {
        unsigned long long ent = slist[e];
        uint32_t t     = (uint32_t)(ent >> 32);
        uint32_t start = (uint32_t)(ent >> 16) & 0xFFFFu;
        uint32_t m     = (uint32_t)ent & 0xFFFFu;
        size_t base = (size_t)t << 15;
        uint32_t id = 0xFFFFFFFFu, k = 0u;
        if (lane < m) {
            id = bidx[base + start + lane];
            k  = bkey ? bkey[base + start + lane] : fkey(task_src((int)t, P, Tg)[id]);
        }
        uint32_t cnt = 0;
        for (uint32_t q = 0; q < m; ++q) {
            uint32_t kq = __shfl(k, (int)q, 64);
            uint32_t iq = __shfl(id, (int)q, 64);
            cnt += (kq < k || (kq == k && iq < id)) ? 1u : 0u;
        }
        if (lane < m) ranks[base + id] = (uint16_t)(start + cnt);
    }
}

// ---------------- K6: per-row exact dot of ranks -> per-row loss (double) ----------------
__global__ void __launch_bounds__(1024) k_dot(const uint16_t* ranks, double* rowloss) {
    int r = blockIdx.x;
    const uint4* pa = (const uint4*)(ranks + (size_t)r * N_COLS);
    const uint4* pb = (const uint4*)(ranks + (size_t)(r + N_ROWS) * N_COLS);
    unsigned long long s = 0;
    for (int j = threadIdx.x; j < N_COLS / 8; j += 1024) {
        uint4 a = pa[j], b = pb[j];
        s += (unsigned long long)((a.x & 0xFFFFu) * (b.x & 0xFFFFu));
        s += (unsigned long long)((a.x >> 16)     * (b.x >> 16));
        s += (unsigned long long)((a.y & 0xFFFFu) * (b.y & 0xFFFFu));
        s += (unsigned long long)((a.y >> 16)     * (b.y >> 16));
        s += (unsigned long long)((a.z & 0xFFFFu) * (b.z & 0xFFFFu));
        s += (unsigned long long)((a.z >> 16)     * (b.z >> 16));
        s += (unsigned long long)((a.w & 0xFFFFu) * (b.w & 0xFFFFu));
        s += (unsigned long long)((a.w >> 16)     * (b.w >> 16));
    }
    for (int off = 32; off; off >>= 1) s += __shfl_down(s, off, 64);
    __shared__ unsigned long long sws[16];
    int w = threadIdx.x >> 6, lane = threadIdx.x & 63;
    if (lane == 0) sws[w] = s;
    __syncthreads();
    if (threadIdx.x == 0) {
        unsigned long long tot = 0;
        for (int i = 0; i < 16; ++i) tot += sws[i];
        double S   = (double)tot;
        double num = S - 32768.0 * 16383.5 * 16383.5;                 // S - n*mu^2 (exact in double)
        double den = 32768.0 * 1073741823.0 / 12.0;                   // n(n^2-1)/12
        rowloss[r] = 1.0 - num / (den + 1e-8);
    }
}

// ---------------- K7: deterministic fixed-order final reduction ----------------
__global__ void __launch_bounds__(256) k_final(const double* rowloss, float* out) {
    __shared__ double s[256];
    s[threadIdx.x] = rowloss[threadIdx.x];
    __syncthreads();
    for (int off = 128; off; off >>= 1) {
        if ((int)threadIdx.x < off) s[threadIdx.x] += s[threadIdx.x + off];
        __syncthreads();
    }
    if (threadIdx.x == 0) out[0] = (float)(s[0] / 256.0);
}

extern "C" void kernel_launch(void* const* d_in, const int* in_sizes, int n_in,
                              void* d_out, int out_size, void* d_ws, size_t ws_size,
                              hipStream_t stream) {
    const float* P  = (const float*)d_in[0];
    const float* Tg = (const float*)d_in[1];
    float* out = (float*)d_out;
    char* ws = (char*)d_ws;
    const size_t MB = 1024 * 1024;

    // layout
    uint32_t* hist = (uint32_t*)(ws);                            // 16 MB (512 tasks x 8192 u32)
    uint32_t* cnts = (uint32_t*)(ws + 16 * MB);                  // 8 B  (listcnt, slistcnt)
    unsigned long long* list  = (unsigned long long*)(ws + 16 * MB + 4096);  // ~3 MB (max 258048 entries)
    unsigned long long* slist = (unsigned long long*)(ws + 19 * MB);         // 8 MB (max 1M entries)

    bool use_bkey = (ws_size >= 156 * MB);
    uint32_t* bkey; uint16_t* bidx; uint16_t* ranks; double* rowloss;
    if (use_bkey) {
        bkey    = (uint32_t*)(ws + 27 * MB);   // 64 MB
        bidx    = (uint16_t*)(ws + 91 * MB);   // 32 MB
        ranks   = (uint16_t*)(ws + 123 * MB);  // 32 MB
        rowloss = (double*)  (ws + 155 * MB);  // 2 KB   -> total ~155 MB
    } else {
        bkey    = nullptr;
        bidx    = (uint16_t*)(ws + 27 * MB);   // 32 MB
        ranks   = (uint16_t*)(ws + 59 * MB);   // 32 MB
        rowloss = (double*)  (ws + 91 * MB);   // 2 KB   -> total ~91 MB
    }

    hipMemsetAsync(cnts, 0, 16, stream);   // only the two list counters need zeroing

    k_hist   <<<N_TASKS, 512, 0, stream>>>(P, Tg, hist);
    k_scan   <<<N_TASKS, 256, 0, stream>>>(hist, cnts, list, slist);
    k_scatter<<<N_TASKS, 512, 0, stream>>>(P, Tg, hist, bkey, bidx);
    k_large  <<<2048,    256, 0, stream>>>(P, Tg, bkey, bidx, ranks, cnts, list);
    k_small  <<<2048,    256, 0, stream>>>(P, Tg, bkey, bidx, ranks, cnts, slist);
    k_dot    <<<N_ROWS, 1024, 0, stream>>>(ranks, rowloss);
    k_final  <<<1,       256, 0, stream>>>(rowloss, out);
}